// Round 1
// baseline (97.880 us; speedup 1.0000x reference)
//
#include <hip/hip_runtime.h>

// Problem constants (from reference setup_inputs):
//   input:            (B=16, S=4096, C=128) fp32
//   shifting_weights: (B=16, T=2048)        fp32
//   out:              (B=16, T=2048, C=128) fp32
//   w[b,t,s] = exp(-(shift[b,t] + s - t)^2 / 0.25) = exp(-4*x^2)
// exp(-4x^2) < 2.3e-16 for |x| >= 3  =>  only a narrow band of s matters.
constexpr int B = 16;
constexpr int S = 4096;
constexpr int C = 128;
constexpr int T = 2048;
constexpr int W = 16;               // window width in s; covers center-7..center+8
constexpr float WIDTH_INV = 4.0f;   // 1 / 0.25

__global__ __launch_bounds__(C) void ShiftingLayer_63247688401341_kernel(
        const float* __restrict__ inp,     // (B,S,C)
        const float* __restrict__ shift,   // (B,T)
        float* __restrict__ out)           // (B,T,C)
{
    const int t = blockIdx.x;
    const int b = blockIdx.y;
    const int c = threadIdx.x;

    const float sh = shift[(size_t)b * T + t];
    // weight is exp(-4*(sh + s - t)^2): peak at s = t - sh
    const float center = (float)t - sh;
    const int s0 = (int)floorf(center) - (W / 2 - 1);

    // Compute the W Gaussian weights once per block (shared across 128 lanes)
    __shared__ float wsh[W];
    if (c < W) {
        const int s = s0 + c;
        const float x = sh + (float)(s - t);
        float w = __expf(-WIDTH_INV * x * x);
        if (s < 0 || s >= S) w = 0.0f;   // out-of-range rows contribute 0
        wsh[c] = w;
    }
    __syncthreads();

    // Block-uniform valid range (no divergence); avoids OOB addresses.
    const int jlo = (s0 < 0) ? -s0 : 0;
    const int jhi = (s0 + W > S) ? (S - s0) : W;

    const float* rowbase = inp + ((size_t)b * S) * C + c;
    float acc = 0.0f;
    #pragma unroll 4
    for (int j = jlo; j < jhi; ++j) {
        acc = fmaf(wsh[j], rowbase[(size_t)(s0 + j) * C], acc);
    }
    out[((size_t)b * T + t) * C + c] = acc;
}

extern "C" void kernel_launch(void* const* d_in, const int* in_sizes, int n_in,
                              void* d_out, int out_size, void* d_ws, size_t ws_size,
                              hipStream_t stream) {
    const float* inp   = (const float*)d_in[0];   // (B,S,C)
    const float* shift = (const float*)d_in[1];   // (B,T)
    float* out = (float*)d_out;                   // (B,T,C)

    dim3 grid(T, B);
    dim3 block(C);
    ShiftingLayer_63247688401341_kernel<<<grid, block, 0, stream>>>(inp, shift, out);
}

// Round 2
// 83.742 us; speedup vs baseline: 1.1688x; 1.1688x over previous
//
#include <hip/hip_runtime.h>

// input: (B=16, S=4096, C=128) fp32; shift: (B=16, T=2048) fp32
// out[b,t,c] = sum_s exp(-4*(shift[b,t]+s-t)^2) * input[b,s,c]
// exp(-4x^2) < 1e-85 for |x| >= 7  =>  16-wide window centered at t-shift is exact in fp32.
constexpr int B = 16;
constexpr int S = 4096;
constexpr int C = 128;
constexpr int T = 2048;
constexpr int W = 16;     // window rows per t
constexpr int TT = 8;     // t-values per block

__global__ __launch_bounds__(256) void ShiftingLayer_63247688401341_kernel(
        const float* __restrict__ inp,     // (B,S,C)
        const float* __restrict__ shift,   // (B,T)
        float* __restrict__ out)           // (B,T,C)
{
    const int b  = blockIdx.y;
    const int t0 = blockIdx.x * TT;

    __shared__ float wsh[TT][W];   // Gaussian weights per (t, window-row)
    __shared__ int   s0sh[TT];     // window start row per t

    // Phase 1: 128 threads compute the 8x16 weight table once per block.
    const int tid = threadIdx.x;
    if (tid < TT * W) {
        const int tt = tid >> 4;          // 0..7
        const int j  = tid & (W - 1);     // 0..15
        const int t  = t0 + tt;
        const float sh = shift[(size_t)b * T + t];
        const int s0 = (int)floorf((float)t - sh) - (W / 2 - 1);
        const int s  = s0 + j;
        const float x = sh + (float)(s - t);
        float w = __expf(-4.0f * x * x);
        if (s < 0 || s >= S) w = 0.0f;    // OOB rows contribute 0
        wsh[tt][j] = w;
        if (j == 0) s0sh[tt] = s0;
    }
    __syncthreads();

    // Phase 2: each thread = one (t, 4-channel group). Fully unrolled window.
    const int tt = tid >> 5;              // 0..7
    const int c4 = (tid & 31) * 4;        // channel group 0,4,...,124
    const int t  = t0 + tt;
    const int s0 = s0sh[tt];

    const float* base = inp + (size_t)b * S * C + c4;
    float4 acc = make_float4(0.f, 0.f, 0.f, 0.f);
    #pragma unroll
    for (int j = 0; j < W; ++j) {
        int srow = s0 + j;
        srow = srow < 0 ? 0 : (srow >= S ? S - 1 : srow);   // clamp; weight=0 when OOB
        const float4 v = *(const float4*)(base + (size_t)srow * C);
        const float w = wsh[tt][j];
        acc.x = fmaf(w, v.x, acc.x);
        acc.y = fmaf(w, v.y, acc.y);
        acc.z = fmaf(w, v.z, acc.z);
        acc.w = fmaf(w, v.w, acc.w);
    }
    *(float4*)(out + ((size_t)b * T + t) * C + c4) = acc;
}

extern "C" void kernel_launch(void* const* d_in, const int* in_sizes, int n_in,
                              void* d_out, int out_size, void* d_ws, size_t ws_size,
                              hipStream_t stream) {
    const float* inp   = (const float*)d_in[0];
    const float* shift = (const float*)d_in[1];
    float* out = (float*)d_out;

    dim3 grid(T / TT, B);   // (256, 16)
    dim3 block(256);
    ShiftingLayer_63247688401341_kernel<<<grid, block, 0, stream>>>(inp, shift, out);
}